// Round 8
// baseline (207.297 us; speedup 1.0000x reference)
//
#include <hip/hip_runtime.h>
#include <hip/hip_bf16.h>
#include <stdint.h>

#define BB 256
#define TT 240
#define CC 512
#define KK 64
#define NCLS 4
#define CHUNK 32
#define NCHUNK 8   // 7 full chunks + 1 half (tvalid=16)
#define THREADS 1024

typedef __attribute__((ext_vector_type(8))) short bf16x8;
typedef __attribute__((ext_vector_type(4))) float f32x4;

__device__ __forceinline__ unsigned short f2bf(float f) {
    union { float f; unsigned int i; } x; x.f = f;
    unsigned int r = x.i + 0x7FFFu + ((x.i >> 16) & 1u);  // RNE, finite only
    return (unsigned short)(r >> 16);
}
// packed fp32x2 -> bf16x2, lo in low half
__device__ __forceinline__ unsigned int pk2cvt(float lo, float hi) {
    union { __hip_bfloat162 h; unsigned int u; } c;
    c.h = __float22bfloat162_rn(float2{lo, hi});
    return c.u;
}
// LDS-only barrier: doesn't drain vmcnt (global prefetch stays in flight)
__device__ __forceinline__ void LB() {
    asm volatile("s_waitcnt lgkmcnt(0)\n\ts_barrier" ::: "memory");
}

struct alignas(16) SMemChunk {
    unsigned short x[CHUNK][520];   // bf16 x chunk, pad 512->520      (33.3 KB)
    unsigned short xT[CC][40];      // transposed, pad 32->40          (41.0 KB)
    float logitsP[2][CHUNK][68];    // k-half partial logits / plain-a (17.4 KB)
    unsigned short aT[KK][40];      // a' = a*rinv bf16                ( 5.1 KB)
};
struct alignas(16) SMemEpi { unsigned short vbuf[KK * CC]; };  // 64 KB
union SMemU { SMemChunk c; SMemEpi e; };

// NOTE: no min-waves arg! (1024,4) made the compiler cap VGPRs at 64 ->
// 6 MB/dispatch scratch spills (round 7). A 1024-thread block already
// forces <=128 VGPR for launchability; let the allocator use them.
__global__ __launch_bounds__(THREADS) void netvlad_kernel(
    const float* __restrict__ inp,    // [B,T,C]
    const float* __restrict__ convw,  // [K,C]
    const float* __restrict__ cent,   // [K,C]
    const float* __restrict__ fcw,    // [NC, K*C]
    const float* __restrict__ fcb,    // [NC]
    float* __restrict__ out)          // [B,NC]
{
    __shared__ SMemU sm;
    __shared__ float sumsq_sh[CHUNK];
    __shared__ float asum[KK];
    __shared__ float ssred[4][KK];
    __shared__ float gred[16];
    __shared__ float fcred[16][NCLS];
    __shared__ float vinv_sh;

    const int tid  = threadIdx.x;
    const int b    = blockIdx.x;
    const int w    = tid >> 6;       // wave 0..15
    const int lane = tid & 63;
    const int grp  = (lane >> 4) & 3;
    const int col  = lane & 15;
    const int cg   = w & 3;          // cluster group
    const int th   = (w >> 2) & 1;   // logits t-tile
    const int kh   = w >> 3;         // logits k-half
    const int cq   = w >> 2;         // VLAD c-quarter

    if (tid < KK) asum[tid] = 0.f;

    f32x4 acc[8];
    #pragma unroll
    for (int j = 0; j < 8; ++j) acc[j] = (f32x4){0.f, 0.f, 0.f, 0.f};

    // conv_w slice: clusters 16cg..+16, k-half kh
    bf16x8 cw[8];
    #pragma unroll
    for (int s = 0; s < 8; ++s) {
        const float* p = convw + (size_t)(cg * 16 + col) * CC + (kh * 8 + s) * 32 + grp * 8;
        float4 a0 = *(const float4*)p;
        float4 a1 = *(const float4*)(p + 4);
        bf16x8 v;
        v[0] = (short)f2bf(a0.x); v[1] = (short)f2bf(a0.y);
        v[2] = (short)f2bf(a0.z); v[3] = (short)f2bf(a0.w);
        v[4] = (short)f2bf(a1.x); v[5] = (short)f2bf(a1.y);
        v[6] = (short)f2bf(a1.z); v[7] = (short)f2bf(a1.w);
        cw[s] = v;
    }

    const size_t ibase = (size_t)b * (TT * CC);

    // prefetch chunk 0 raw fp32
    float4 r0[2], r1[2];
    #pragma unroll
    for (int i = 0; i < 2; ++i) {
        int g = tid + i * THREADS;
        int t = g >> 6, c8 = (g & 63) << 3;
        const float* p = inp + ibase + (size_t)t * CC + c8;
        r0[i] = *(const float4*)p;
        r1[i] = *(const float4*)(p + 4);
    }

    for (int ch = 0; ch < NCHUNK; ++ch) {
        const int t0 = ch * CHUNK;
        const int tvalid = (TT - t0 < CHUNK) ? (TT - t0) : CHUNK;

        // ---- phase A: stage regs -> bf16 LDS + row sumsq; issue next loads ----
        #pragma unroll
        for (int i = 0; i < 2; ++i) {
            int g = tid + i * THREADS;
            int t = g >> 6, c8 = (g & 63) << 3;   // t wave-uniform (= w + 16i)
            float4 u0 = r0[i], u1 = r1[i];
            uint4 val = (uint4){pk2cvt(u0.x, u0.y), pk2cvt(u0.z, u0.w),
                                pk2cvt(u1.x, u1.y), pk2cvt(u1.z, u1.w)};
            float s = u0.x*u0.x + u0.y*u0.y + u0.z*u0.z + u0.w*u0.w
                    + u1.x*u1.x + u1.y*u1.y + u1.z*u1.z + u1.w*u1.w;
            if (t >= tvalid) { val = (uint4){0u,0u,0u,0u}; s = 0.f; }
            *(uint4*)&sm.c.x[t][c8] = val;
            s += __shfl_xor(s, 1);  s += __shfl_xor(s, 2);  s += __shfl_xor(s, 4);
            s += __shfl_xor(s, 8);  s += __shfl_xor(s, 16); s += __shfl_xor(s, 32);
            if (lane == 0) sumsq_sh[t] = s;
        }
        if (ch + 1 < NCHUNK) {
            int nt0 = t0 + CHUNK;
            #pragma unroll
            for (int i = 0; i < 2; ++i) {
                int g = tid + i * THREADS;
                int t = g >> 6, c8 = (g & 63) << 3;
                int gt = nt0 + t; if (gt > TT - 1) gt = TT - 1;  // clamp address only
                const float* p = inp + ibase + (size_t)gt * CC + c8;
                r0[i] = *(const float4*)p;
                r1[i] = *(const float4*)(p + 4);
            }
        }
        LB();  // x + sumsq ready

        // ---- phase B: transpose (all 16 waves) + partial logits ----
        {
            int c = tid & 511, th2 = tid >> 9;
            #pragma unroll
            for (int tb2 = 0; tb2 < 2; ++tb2) {
                int tb = th2 * 2 + tb2;
                bf16x8 v;
                #pragma unroll
                for (int j = 0; j < 8; ++j) v[j] = (short)sm.c.x[tb * 8 + j][c];
                *(bf16x8*)&sm.c.xT[c][tb * 8] = v;
            }
        }
        {
            f32x4 lt = (f32x4){0.f, 0.f, 0.f, 0.f};
            #pragma unroll
            for (int s = 0; s < 8; ++s) {
                bf16x8 bb = *(const bf16x8*)&sm.c.x[th * 16 + col][(kh * 8 + s) * 32 + grp * 8];
                lt = __builtin_amdgcn_mfma_f32_16x16x32_bf16(cw[s], bb, lt, 0, 0, 0);
            }
            #pragma unroll
            for (int r = 0; r < 4; ++r)
                sm.c.logitsP[kh][th * 16 + col][cg * 16 + grp * 4 + r] = lt[r];
        }
        LB();  // xT + logitsP ready

        // ---- phase C: softmax per t (16 threads/col, threads 0..511) ----
        if (tid < 512) {
            int t = tid >> 4, part = tid & 15;
            float rinv = 1.f / fmaxf(sqrtf(sumsq_sh[t]), 1e-12f);
            rinv = (t < tvalid) ? rinv : 0.f;

            float l[4]; float lmax = -1e30f;
            #pragma unroll
            for (int q = 0; q < 4; ++q) {
                l[q] = (sm.c.logitsP[0][t][q * 16 + part] +
                        sm.c.logitsP[1][t][q * 16 + part]) * rinv;
                lmax = fmaxf(lmax, l[q]);
            }
            lmax = fmaxf(lmax, __shfl_xor(lmax, 1));
            lmax = fmaxf(lmax, __shfl_xor(lmax, 2));
            lmax = fmaxf(lmax, __shfl_xor(lmax, 4));
            lmax = fmaxf(lmax, __shfl_xor(lmax, 8));
            float es = 0.f;
            #pragma unroll
            for (int q = 0; q < 4; ++q) { l[q] = __expf(l[q] - lmax); es += l[q]; }
            es += __shfl_xor(es, 1); es += __shfl_xor(es, 2);
            es += __shfl_xor(es, 4); es += __shfl_xor(es, 8);
            float is = 1.f / es;
            #pragma unroll
            for (int q = 0; q < 4; ++q) {
                float a = l[q] * is;
                sm.c.logitsP[0][t][q * 16 + part] = a;                      // plain a
                sm.c.aT[q * 16 + part][t] = (unsigned short)f2bf(a * rinv); // 0 if masked
            }
        }
        LB();  // aT + plain-a ready

        // ---- phase D: asum + VLAD ----
        if (tid < KK) {
            float s = 0.f;
            for (int t = 0; t < tvalid; ++t) s += sm.c.logitsP[0][t][tid];
            asum[tid] += s;
        }
        {
            bf16x8 af = *(const bf16x8*)&sm.c.aT[cg * 16 + col][grp * 8];
            #pragma unroll
            for (int j = 0; j < 8; ++j) {
                bf16x8 bf = *(const bf16x8*)&sm.c.xT[cq * 128 + j * 16 + col][grp * 8];
                acc[j] = __builtin_amdgcn_mfma_f32_16x16x32_bf16(af, bf, acc[j], 0, 0, 0);
            }
        }
    }

    // ===== epilogue =====
    LB();

    // centroid subtract + per-cluster partial sumsq (c-quarter per wave)
    #pragma unroll
    for (int r = 0; r < 4; ++r) {
        int cl = cg * 16 + grp * 4 + r;
        float as = asum[cl];
        float ss = 0.f;
        #pragma unroll
        for (int j = 0; j < 8; ++j) {
            int c = cq * 128 + j * 16 + col;
            float v = acc[j][r] - as * cent[(size_t)cl * CC + c];
            acc[j][r] = v;
            ss += v * v;
        }
        ss += __shfl_xor(ss, 1); ss += __shfl_xor(ss, 2);
        ss += __shfl_xor(ss, 4); ss += __shfl_xor(ss, 8);
        if (col == 0) ssred[cq][cl] = ss;
    }
    LB();

    float contrib = 0.f;
    #pragma unroll
    for (int r = 0; r < 4; ++r) {
        int cl = cg * 16 + grp * 4 + r;
        float ss = ssred[0][cl] + ssred[1][cl] + ssred[2][cl] + ssred[3][cl];
        float inv = 1.f / fmaxf(sqrtf(ss), 1e-12f);
        #pragma unroll
        for (int j = 0; j < 8; ++j) {
            float v = acc[j][r] * inv;
            acc[j][r] = v;
            contrib += v * v;
        }
    }
    #pragma unroll
    for (int m = 1; m < 64; m <<= 1) contrib += __shfl_xor(contrib, m);
    if (lane == 0) gred[w] = contrib;
    LB();
    if (tid == 0) {
        float tot = 0.f;
        #pragma unroll
        for (int i = 0; i < 16; ++i) tot += gred[i];
        vinv_sh = 1.f / fmaxf(sqrtf(tot), 1e-12f);
    }
    LB();

    // write normalized v (bf16) to LDS — chunk arrays dead now
    {
        float vinv = vinv_sh;
        #pragma unroll
        for (int r = 0; r < 4; ++r) {
            int cl = cg * 16 + grp * 4 + r;
            #pragma unroll
            for (int j = 0; j < 8; ++j) {
                int c = cq * 128 + j * 16 + col;
                sm.e.vbuf[cl * CC + c] = f2bf(acc[j][r] * vinv);
            }
        }
    }
    LB();

    // FC: NCLS dots of length 32768
    float pacc[NCLS] = {0.f, 0.f, 0.f, 0.f};
    #pragma unroll
    for (int i = 0; i < 4; ++i) {
        int idx = i * 8192 + tid * 8;
        bf16x8 vv = *(const bf16x8*)&sm.e.vbuf[idx];
        float vf[8];
        #pragma unroll
        for (int h = 0; h < 8; ++h) {
            union { unsigned int u; float f; } cvt;
            cvt.u = ((unsigned int)(unsigned short)vv[h]) << 16;
            vf[h] = cvt.f;
        }
        #pragma unroll
        for (int nc = 0; nc < NCLS; ++nc) {
            const float* wp = fcw + (size_t)nc * (KK * CC) + idx;
            float4 w0 = *(const float4*)wp;
            float4 w1 = *(const float4*)(wp + 4);
            pacc[nc] += vf[0] * w0.x + vf[1] * w0.y + vf[2] * w0.z + vf[3] * w0.w
                      + vf[4] * w1.x + vf[5] * w1.y + vf[6] * w1.z + vf[7] * w1.w;
        }
    }
    #pragma unroll
    for (int nc = 0; nc < NCLS; ++nc) {
        #pragma unroll
        for (int m = 1; m < 64; m <<= 1) pacc[nc] += __shfl_xor(pacc[nc], m);
    }
    if (lane == 0) {
        #pragma unroll
        for (int nc = 0; nc < NCLS; ++nc) fcred[w][nc] = pacc[nc];
    }
    LB();
    if (tid < NCLS) {
        float s = fcb[tid];
        #pragma unroll
        for (int ww = 0; ww < 16; ++ww) s += fcred[ww][tid];
        out[b * NCLS + tid] = 1.f / (1.f + __expf(-s));
    }
}

extern "C" void kernel_launch(void* const* d_in, const int* in_sizes, int n_in,
                              void* d_out, int out_size, void* d_ws, size_t ws_size,
                              hipStream_t stream) {
    const float* inp   = (const float*)d_in[0];
    const float* convw = (const float*)d_in[1];
    const float* cent  = (const float*)d_in[2];
    const float* fcw   = (const float*)d_in[3];
    const float* fcb   = (const float*)d_in[4];
    float* o = (float*)d_out;
    netvlad_kernel<<<BB, THREADS, 0, stream>>>(inp, convw, cent, fcw, fcb, o);
}